// Round 6
// baseline (100.548 us; speedup 1.0000x reference)
//
#include <hip/hip_runtime.h>
#include <hip/hip_bf16.h>

typedef __attribute__((ext_vector_type(8)))  short bf16x8;
typedef __attribute__((ext_vector_type(16))) float f32x16;
typedef __attribute__((ext_vector_type(4)))  float f32x4;
typedef __attribute__((ext_vector_type(2)))  unsigned int u32x2;
typedef __attribute__((ext_vector_type(4)))  unsigned int u32x4;

#define NN 4096
#define CH 256
#define CQ 32

union UB { u32x4 u; bf16x8 h; };

static __device__ __forceinline__ ushort f2bf(float f) {
    __hip_bfloat16 h = __float2bfloat16(f);
    return *reinterpret_cast<ushort*>(&h);
}
static __device__ __forceinline__ uint pack2bf(float a, float b) {
    return (uint)f2bf(a) | ((uint)f2bf(b) << 16);
}
static __device__ __forceinline__ int swz(int n) {   // 3-bit 16B-slot swizzle
    return ((n & 7) ^ ((n >> 3) & 7)) << 4;
}

// ---------------------------------------------------------------------------
// Fused Q/K/V projection, bf16 MFMA. grid (32 nblk, 5 chb, 4 b), block 256.
// chb 0..3 -> v channels chb*64..+64 ([C][N] bf16); chb 4 -> q (wc=0, scaled
// by log2e) and k (wc=1), written transposed [N][32] bf16 for MFMA frags.
// ---------------------------------------------------------------------------
__global__ __launch_bounds__(256) void proj_mfma(
    const float* __restrict__ x,
    const float* __restrict__ Wq, const float* __restrict__ bq,
    const float* __restrict__ Wk, const float* __restrict__ bk,
    const float* __restrict__ Wv, const float* __restrict__ bv,
    ushort* __restrict__ qT, ushort* __restrict__ kT, ushort* __restrict__ v)
{
    const int nblk = blockIdx.x;
    const int chb  = blockIdx.y;
    const int b    = blockIdx.z;
    const int t    = threadIdx.x;
    const int w    = t >> 6;
    const int wc   = w >> 1, wn = w & 1;
    const int lane = t & 63;
    const int l31  = lane & 31;
    const int h5   = lane >> 5;

    __shared__ ushort Wl[64 * 256];     // 32 KB  [ch][c] bf16, 512B rows, swizzled
    __shared__ ushort Xl[128 * 64];     // 16 KB  [n][c]  bf16, 128B rows, swizzled

    // ---- stage W (64 out-ch x 256 c) fp32 -> bf16, once ----
    {
        const int ch  = t >> 2;
        const int c0  = (t & 3) * 64;
        const int chg = chb * 64 + ch;
        const float* wr; float sc = 1.0f;
        if (chg < 256)      wr = Wv + (size_t)chg * CH;
        else if (chg < 288) { wr = Wq + (size_t)(chg - 256) * CH; sc = 1.44269504f; }
        else                wr = Wk + (size_t)(chg - 288) * CH;
        const int sw = swz(ch);
#pragma unroll
        for (int j = 0; j < 16; ++j) {
            const int c = c0 + 4 * j;
            float4 f = *reinterpret_cast<const float4*>(wr + c);
            u32x2 p; p.x = pack2bf(f.x * sc, f.y * sc); p.y = pack2bf(f.z * sc, f.w * sc);
            *reinterpret_cast<u32x2*>((char*)Wl + ((ch * 512 + c * 2) ^ sw)) = p;
        }
    }

    const f32x16 z16 = {0,0,0,0, 0,0,0,0, 0,0,0,0, 0,0,0,0};
    f32x16 acc0 = z16, acc1 = z16;
    const float* xb = x + (size_t)b * CH * NN + nblk * 128;

    for (int cs = 0; cs < 4; ++cs) {
        if (cs) __syncthreads();
        // ---- stage x[cs*64 .. +64) transposed -> Xl[n][c], bf16 ----
#pragma unroll
        for (int half = 0; half < 2; ++half) {
            const int cl0 = half * 32 + 4 * (t >> 5);
            const int nl0 = 4 * (t & 31);
            const float4 r0 = *reinterpret_cast<const float4*>(xb + (size_t)(cs*64 + cl0 + 0) * NN + nl0);
            const float4 r1 = *reinterpret_cast<const float4*>(xb + (size_t)(cs*64 + cl0 + 1) * NN + nl0);
            const float4 r2 = *reinterpret_cast<const float4*>(xb + (size_t)(cs*64 + cl0 + 2) * NN + nl0);
            const float4 r3 = *reinterpret_cast<const float4*>(xb + (size_t)(cs*64 + cl0 + 3) * NN + nl0);
#pragma unroll
            for (int e = 0; e < 4; ++e) {
                const int nl = nl0 + e;
                u32x2 p;
                p.x = pack2bf(((const float*)&r0)[e], ((const float*)&r1)[e]);
                p.y = pack2bf(((const float*)&r2)[e], ((const float*)&r3)[e]);
                *reinterpret_cast<u32x2*>((char*)Xl + ((nl * 128 + cl0 * 2) ^ swz(nl))) = p;
            }
        }
        __syncthreads();
        // ---- 4 K-steps of 16 ----
#pragma unroll
        for (int kl = 0; kl < 4; ++kl) {
            const int ks  = cs * 4 + kl;
            const int chl = 32 * wc + l31;
            const bf16x8 af = *reinterpret_cast<const bf16x8*>(
                (char*)Wl + ((chl * 512 + ks * 32 + h5 * 16) ^ swz(chl)));
            {
                const int nl = 64 * wn + l31;
                const bf16x8 bfv = *reinterpret_cast<const bf16x8*>(
                    (char*)Xl + ((nl * 128 + kl * 32 + h5 * 16) ^ swz(nl)));
                acc0 = __builtin_amdgcn_mfma_f32_32x32x16_bf16(af, bfv, acc0, 0, 0, 0);
            }
            {
                const int nl = 64 * wn + 32 + l31;
                const bf16x8 bfv = *reinterpret_cast<const bf16x8*>(
                    (char*)Xl + ((nl * 128 + kl * 32 + h5 * 16) ^ swz(nl)));
                acc1 = __builtin_amdgcn_mfma_f32_32x32x16_bf16(af, bfv, acc1, 0, 0, 0);
            }
        }
    }

    // ---- epilogue: bias + store ----
    const int chbase = chb * 64 + 32 * wc;
    if (chb < 4) {
        ushort* vb = v + (size_t)b * CH * NN;
#pragma unroll
        for (int nt = 0; nt < 2; ++nt) {
            const f32x16 a = nt ? acc1 : acc0;
            const int n = nblk * 128 + 64 * wn + 32 * nt + l31;
#pragma unroll
            for (int r = 0; r < 16; ++r) {
                const int row = (r & 3) + 8 * (r >> 2) + 4 * h5;
                vb[(size_t)(chbase + row) * NN + n] = f2bf(a[r] + bv[chbase + row]);
            }
        }
    } else {
        ushort* dst = (wc == 0 ? qT : kT) + (size_t)b * NN * CQ;
        const float* bs = (wc == 0 ? bq : bk);
        const float bsc = (wc == 0) ? 1.44269504f : 1.0f;
#pragma unroll
        for (int nt = 0; nt < 2; ++nt) {
            const f32x16 a = nt ? acc1 : acc0;
            const int n = nblk * 128 + 64 * wn + 32 * nt + l31;
#pragma unroll
            for (int r = 0; r < 16; r += 2) {
                const int row = (r & 3) + 8 * (r >> 2) + 4 * h5;   // even
                *reinterpret_cast<uint*>(dst + (size_t)n * CQ + row) =
                    pack2bf(a[r] + bs[row] * bsc, a[r + 1] + bs[row + 1] * bsc);
            }
        }
    }
}

// ---------------------------------------------------------------------------
// Flash attention v5: BARRIER-FREE main loop. Wave (kg,cg) owns keys
// 1024*kg..+1024 x channels 128*cg..+128 x all 64 queries. QK^T duplicated
// across the cg pair (cheap) so P never leaves the wave: exp+pack+permlane
// in-register feeds PV directly. One 128KB LDS tree-reduction over kg at the
// very end (3 barriers total). grid 256 (batch locked to XCD pair),
// block 512 (8 waves, 2/SIMD, 256-VGPR budget).
// ---------------------------------------------------------------------------
__global__ __attribute__((amdgpu_flat_work_group_size(512, 512), amdgpu_waves_per_eu(2, 2)))
void attn_v5(
    const ushort* __restrict__ qT, const ushort* __restrict__ kT,
    const ushort* __restrict__ v, float* __restrict__ out)
{
    const int bid  = blockIdx.x;
    const int xcd  = bid & 7;
    const int b    = xcd >> 1;                       // batch locked to XCD pair
    const int qblk = (bid >> 3) + 32 * (xcd & 1);
    const int i0   = qblk * 64;

    const int t    = threadIdx.x;
    const int w    = t >> 6;
    const int kg   = w >> 1;          // key group 0..3 (1024 keys each)
    const int cg   = w & 1;           // channel half 0..1 (128 ch each)
    const int lane = t & 63;
    const int l31  = lane & 31;
    const int h5   = lane >> 5;

    __shared__ f32x4 cbuf[2][2][4][2][4][64];   // 128 KB kg-reduction buffer
    __shared__ float red[2][4][32];             // 1 KB denominators [qt][kg][q]

    const ushort* qTb   = qT + (size_t)b * NN * CQ;
    const ushort* kbase = kT + (size_t)b * NN * CQ + (size_t)(kg * 1024 + l31) * CQ;
    const ushort* vbase = v + ((size_t)b * CH + 128 * cg + l31) * NN + kg * 1024;

    // Q B-frags (col = query), both halves, contraction 32 in 2 ksteps
    bf16x8 qf[2][2];
#pragma unroll
    for (int qt = 0; qt < 2; ++qt)
#pragma unroll
        for (int ks = 0; ks < 2; ++ks)
            qf[qt][ks] = *reinterpret_cast<const bf16x8*>(
                qTb + (size_t)(i0 + 32 * qt + l31) * CQ + 16 * ks + 8 * h5);

    const f32x16 z16 = {0,0,0,0, 0,0,0,0, 0,0,0,0, 0,0,0,0};
    f32x16 acc[4][2];
#pragma unroll
    for (int ct = 0; ct < 4; ++ct) { acc[ct][0] = z16; acc[ct][1] = z16; }
    float ts0 = 0.f, ts1 = 0.f;

    // K A-frags for it=0 (row = key kg*1024 + l31)
    bf16x8 kf0 = *reinterpret_cast<const bf16x8*>(kbase + 8 * h5);
    bf16x8 kf1 = *reinterpret_cast<const bf16x8*>(kbase + 16 + 8 * h5);

    auto expack = [&](const f32x16& s, float& ts, bf16x8& b0, bf16x8& b1) {
        float p[16];
#pragma unroll
        for (int r = 0; r < 16; ++r) p[r] = __builtin_exp2f(s[r]);
        ts += (((p[0]+p[1])+(p[2]+p[3])) + ((p[4]+p[5])+(p[6]+p[7])))
            + (((p[8]+p[9])+(p[10]+p[11])) + ((p[12]+p[13])+(p[14]+p[15])));
        const uint pk0 = pack2bf(p[0],  p[1]);
        const uint pk1 = pack2bf(p[2],  p[3]);
        const uint pk2 = pack2bf(p[4],  p[5]);
        const uint pk3 = pack2bf(p[6],  p[7]);
        const uint pk4 = pack2bf(p[8],  p[9]);
        const uint pk5 = pack2bf(p[10], p[11]);
        const uint pk6 = pack2bf(p[12], p[13]);
        const uint pk7 = pack2bf(p[14], p[15]);
        const u32x2 s02 = __builtin_amdgcn_permlane32_swap(pk0, pk2, false, false);
        const u32x2 s13 = __builtin_amdgcn_permlane32_swap(pk1, pk3, false, false);
        const u32x2 s46 = __builtin_amdgcn_permlane32_swap(pk4, pk6, false, false);
        const u32x2 s57 = __builtin_amdgcn_permlane32_swap(pk5, pk7, false, false);
        UB u0; u0.u = u32x4{ s02.x, s13.x, s02.y, s13.y };   // keys 8h5..+7   (ks0)
        UB u1; u1.u = u32x4{ s46.x, s57.x, s46.y, s57.y };   // keys 16+8h5..+7 (ks1)
        b0 = u0.h; b1 = u1.h;
    };

    for (int it = 0; it < 32; ++it) {
        const int j0 = it * 32;

        // ---- issue V frags for this iter (covered by S + expack below) ----
        bf16x8 vf[4][2];
#pragma unroll
        for (int ct = 0; ct < 4; ++ct) {
            const ushort* vr = vbase + (size_t)(32 * ct) * NN + j0;
            vf[ct][0] = *reinterpret_cast<const bf16x8*>(vr + 8 * h5);
            vf[ct][1] = *reinterpret_cast<const bf16x8*>(vr + 16 + 8 * h5);
        }
        __builtin_amdgcn_sched_barrier(0);   // keep V issues above the S phase

        // ---- swapped S = K·Q^T on this wave's private 32-key chunk ----
        f32x16 s0 = __builtin_amdgcn_mfma_f32_32x32x16_bf16(kf0, qf[0][0], z16, 0, 0, 0);
        s0 = __builtin_amdgcn_mfma_f32_32x32x16_bf16(kf1, qf[0][1], s0, 0, 0, 0);
        f32x16 s1 = __builtin_amdgcn_mfma_f32_32x32x16_bf16(kf0, qf[1][0], z16, 0, 0, 0);
        s1 = __builtin_amdgcn_mfma_f32_32x32x16_bf16(kf1, qf[1][1], s1, 0, 0, 0);

        // ---- prefetch K frags for next iter ----
        if (it != 31) {
            const ushort* kr = kbase + (size_t)(j0 + 32) * CQ;
            kf0 = *reinterpret_cast<const bf16x8*>(kr + 8 * h5);
            kf1 = *reinterpret_cast<const bf16x8*>(kr + 16 + 8 * h5);
        }

        // ---- exp + pack + permlane redistribute, fully in-register ----
        bf16x8 p00, p01, p10, p11;
        expack(s0, ts0, p00, p01);
        expack(s1, ts1, p10, p11);

        // ---- PV on own keys / own channels ----
#pragma unroll
        for (int ct = 0; ct < 4; ++ct) {
            acc[ct][0] = __builtin_amdgcn_mfma_f32_32x32x16_bf16(vf[ct][0], p00, acc[ct][0], 0, 0, 0);
            acc[ct][0] = __builtin_amdgcn_mfma_f32_32x32x16_bf16(vf[ct][1], p01, acc[ct][0], 0, 0, 0);
            acc[ct][1] = __builtin_amdgcn_mfma_f32_32x32x16_bf16(vf[ct][0], p10, acc[ct][1], 0, 0, 0);
            acc[ct][1] = __builtin_amdgcn_mfma_f32_32x32x16_bf16(vf[ct][1], p11, acc[ct][1], 0, 0, 0);
        }
    }

    // ---- denominators: sum key-halves, publish per-kg partials (cg0 only) ----
    ts0 += __shfl_xor(ts0, 32);
    ts1 += __shfl_xor(ts1, 32);
    if (cg == 0 && lane < 32) { red[0][kg][l31] = ts0; red[1][kg][l31] = ts1; }

    // ---- kg tree-reduction of acc through LDS (3 barriers) ----
    auto writeC = [&](int pair) {
#pragma unroll
        for (int ct = 0; ct < 4; ++ct)
#pragma unroll
            for (int qt = 0; qt < 2; ++qt)
#pragma unroll
                for (int rg = 0; rg < 4; ++rg) {
                    f32x4 vv = { acc[ct][qt][4*rg],   acc[ct][qt][4*rg+1],
                                 acc[ct][qt][4*rg+2], acc[ct][qt][4*rg+3] };
                    cbuf[pair][cg][ct][qt][rg][lane] = vv;
                }
    };
    auto addC = [&](int pair) {
#pragma unroll
        for (int ct = 0; ct < 4; ++ct)
#pragma unroll
            for (int qt = 0; qt < 2; ++qt)
#pragma unroll
                for (int rg = 0; rg < 4; ++rg) {
                    const f32x4 vv = cbuf[pair][cg][ct][qt][rg][lane];
                    acc[ct][qt][4*rg]   += vv.x;
                    acc[ct][qt][4*rg+1] += vv.y;
                    acc[ct][qt][4*rg+2] += vv.z;
                    acc[ct][qt][4*rg+3] += vv.w;
                }
    };

    if (kg >= 2) writeC(kg - 2);
    __syncthreads();
    if (kg < 2) addC(kg);
    __syncthreads();
    if (kg == 1) writeC(1);
    __syncthreads();
    if (kg == 0) {
        addC(1);
        const float inv0 = 1.0f / (red[0][0][l31] + red[0][1][l31] + red[0][2][l31] + red[0][3][l31]);
        const float inv1 = 1.0f / (red[1][0][l31] + red[1][1][l31] + red[1][2][l31] + red[1][3][l31]);
        float* ob = out + (size_t)b * CH * NN + i0;
#pragma unroll
        for (int ct = 0; ct < 4; ++ct)
#pragma unroll
            for (int qt = 0; qt < 2; ++qt) {
                const float inv = qt ? inv1 : inv0;
#pragma unroll
                for (int r = 0; r < 16; ++r) {
                    const int chl = 128 * cg + 32 * ct + (r & 3) + 8 * (r >> 2) + 4 * h5;
                    ob[(size_t)chl * NN + 32 * qt + l31] = acc[ct][qt][r] * inv;
                }
            }
    }
}

extern "C" void kernel_launch(void* const* d_in, const int* in_sizes, int n_in,
                              void* d_out, int out_size, void* d_ws, size_t ws_size,
                              hipStream_t stream) {
    const float* x  = (const float*)d_in[0];
    const float* Wq = (const float*)d_in[1];
    const float* bq = (const float*)d_in[2];
    const float* Wk = (const float*)d_in[3];
    const float* bk = (const float*)d_in[4];
    const float* Wv = (const float*)d_in[5];
    const float* bv = (const float*)d_in[6];
    float* out = (float*)d_out;

    ushort* ws = (ushort*)d_ws;
    ushort* qTw = ws;                                  // 4*4096*32 bf16 = 1 MB
    ushort* kTw = qTw + (size_t)4 * NN * CQ;           // 1 MB
    ushort* vw  = kTw + (size_t)4 * NN * CQ;           // 4*256*4096 bf16 = 8 MB

    proj_mfma<<<dim3(32, 5, 4), 256, 0, stream>>>(x, Wq, bq, Wk, bk, Wv, bv, qTw, kTw, vw);
    attn_v5<<<dim3(256), 512, 0, stream>>>(qTw, kTw, vw, out);
}

// Round 7
// 83.991 us; speedup vs baseline: 1.1971x; 1.1971x over previous
//
#include <hip/hip_runtime.h>
#include <hip/hip_bf16.h>

typedef __attribute__((ext_vector_type(8)))  short bf16x8;
typedef __attribute__((ext_vector_type(16))) float f32x16;
typedef __attribute__((ext_vector_type(4)))  float f32x4;
typedef __attribute__((ext_vector_type(2)))  unsigned int u32x2;
typedef __attribute__((ext_vector_type(4)))  unsigned int u32x4;

#define NN 4096
#define CH 256
#define CQ 32

union UB { u32x4 u; bf16x8 h; };

static __device__ __forceinline__ ushort f2bf(float f) {
    __hip_bfloat16 h = __float2bfloat16(f);
    return *reinterpret_cast<ushort*>(&h);
}
static __device__ __forceinline__ uint pack2bf(float a, float b) {
    return (uint)f2bf(a) | ((uint)f2bf(b) << 16);
}
static __device__ __forceinline__ int swz(int n) {   // 3-bit 16B-slot swizzle
    return ((n & 7) ^ ((n >> 3) & 7)) << 4;
}

// ---------------------------------------------------------------------------
// Fragment-tiled workspace layouts (all bf16, 32x32 tiles of 1024 ushorts,
// byte offset inside tile = lane*16 + frag*1024, lane = row%32 + 32*((col>>3)&1)):
//   Vf[b][ct=ch/32][kt=key/32] : off(ch,key) = ((key>>4)&1)*512u + ((key>>3)&1)*256u
//                                             + (ch&31)*8u + (key&7)   [ushort units]
//   kTf[b][kt=key/32]          : off(key,ch) = ((ch>>4)&1)*512u + ((ch>>3)&1)*256u
//                                             + (key&31)*8u + (ch&7)
//   qTf[b][qt=q/32]            : same as kTf with key->q
// A frag load in attn is then *(bf16x8*)(tile_base + frag*512u + lane*8u):
// 64 lanes x 16B = 16 FULL 64B cache lines (coalesced), vs 32 half-lines before.
// ---------------------------------------------------------------------------

// Fused Q/K/V projection, bf16 MFMA. grid (32 nblk, 5 chb, 4 b), block 256.
__global__ __launch_bounds__(256) void proj_mfma(
    const float* __restrict__ x,
    const float* __restrict__ Wq, const float* __restrict__ bq,
    const float* __restrict__ Wk, const float* __restrict__ bk,
    const float* __restrict__ Wv, const float* __restrict__ bv,
    ushort* __restrict__ qT, ushort* __restrict__ kT, ushort* __restrict__ v)
{
    const int nblk = blockIdx.x;
    const int chb  = blockIdx.y;
    const int b    = blockIdx.z;
    const int t    = threadIdx.x;
    const int w    = t >> 6;
    const int wc   = w >> 1, wn = w & 1;
    const int lane = t & 63;
    const int l31  = lane & 31;
    const int h5   = lane >> 5;

    __shared__ ushort Wl[64 * 256];     // 32 KB  [ch][c] bf16, 512B rows, swizzled
    __shared__ ushort Xl[128 * 64];     // 16 KB  [n][c]  bf16, 128B rows, swizzled

    // ---- stage W (64 out-ch x 256 c) fp32 -> bf16, once ----
    {
        const int ch  = t >> 2;
        const int c0  = (t & 3) * 64;
        const int chg = chb * 64 + ch;
        const float* wr; float sc = 1.0f;
        if (chg < 256)      wr = Wv + (size_t)chg * CH;
        else if (chg < 288) { wr = Wq + (size_t)(chg - 256) * CH; sc = 1.44269504f; }
        else                wr = Wk + (size_t)(chg - 288) * CH;
        const int sw = swz(ch);
#pragma unroll
        for (int j = 0; j < 16; ++j) {
            const int c = c0 + 4 * j;
            float4 f = *reinterpret_cast<const float4*>(wr + c);
            u32x2 p; p.x = pack2bf(f.x * sc, f.y * sc); p.y = pack2bf(f.z * sc, f.w * sc);
            *reinterpret_cast<u32x2*>((char*)Wl + ((ch * 512 + c * 2) ^ sw)) = p;
        }
    }

    const f32x16 z16 = {0,0,0,0, 0,0,0,0, 0,0,0,0, 0,0,0,0};
    f32x16 acc0 = z16, acc1 = z16;
    const float* xb = x + (size_t)b * CH * NN + nblk * 128;

    for (int cs = 0; cs < 4; ++cs) {
        if (cs) __syncthreads();
#pragma unroll
        for (int half = 0; half < 2; ++half) {
            const int cl0 = half * 32 + 4 * (t >> 5);
            const int nl0 = 4 * (t & 31);
            const float4 r0 = *reinterpret_cast<const float4*>(xb + (size_t)(cs*64 + cl0 + 0) * NN + nl0);
            const float4 r1 = *reinterpret_cast<const float4*>(xb + (size_t)(cs*64 + cl0 + 1) * NN + nl0);
            const float4 r2 = *reinterpret_cast<const float4*>(xb + (size_t)(cs*64 + cl0 + 2) * NN + nl0);
            const float4 r3 = *reinterpret_cast<const float4*>(xb + (size_t)(cs*64 + cl0 + 3) * NN + nl0);
#pragma unroll
            for (int e = 0; e < 4; ++e) {
                const int nl = nl0 + e;
                u32x2 p;
                p.x = pack2bf(((const float*)&r0)[e], ((const float*)&r1)[e]);
                p.y = pack2bf(((const float*)&r2)[e], ((const float*)&r3)[e]);
                *reinterpret_cast<u32x2*>((char*)Xl + ((nl * 128 + cl0 * 2) ^ swz(nl))) = p;
            }
        }
        __syncthreads();
#pragma unroll
        for (int kl = 0; kl < 4; ++kl) {
            const int ks  = cs * 4 + kl;
            const int chl = 32 * wc + l31;
            const bf16x8 af = *reinterpret_cast<const bf16x8*>(
                (char*)Wl + ((chl * 512 + ks * 32 + h5 * 16) ^ swz(chl)));
            {
                const int nl = 64 * wn + l31;
                const bf16x8 bfv = *reinterpret_cast<const bf16x8*>(
                    (char*)Xl + ((nl * 128 + kl * 32 + h5 * 16) ^ swz(nl)));
                acc0 = __builtin_amdgcn_mfma_f32_32x32x16_bf16(af, bfv, acc0, 0, 0, 0);
            }
            {
                const int nl = 64 * wn + 32 + l31;
                const bf16x8 bfv = *reinterpret_cast<const bf16x8*>(
                    (char*)Xl + ((nl * 128 + kl * 32 + h5 * 16) ^ swz(nl)));
                acc1 = __builtin_amdgcn_mfma_f32_32x32x16_bf16(af, bfv, acc1, 0, 0, 0);
            }
        }
    }

    // ---- epilogue: bias + store in fragment-tiled layouts ----
    const int chbase = chb * 64 + 32 * wc;
    if (chb < 4) {
        ushort* vtb = v + (size_t)b * 8 * 128 * 1024;
#pragma unroll
        for (int nt = 0; nt < 2; ++nt) {
            const f32x16 a = nt ? acc1 : acc0;
            const int key = nblk * 128 + 64 * wn + 32 * nt + l31;
            const size_t kb2 = (size_t)(key >> 5) * 1024
                             + ((key >> 4) & 1) * 512 + ((key >> 3) & 1) * 256 + (key & 7);
#pragma unroll
            for (int r = 0; r < 16; ++r) {
                const int ch = chbase + (r & 3) + 8 * (r >> 2) + 4 * h5;
                vtb[(size_t)(ch >> 5) * 128 * 1024 + kb2 + (ch & 31) * 8] = f2bf(a[r] + bv[ch]);
            }
        }
    } else {
        ushort* dst = (wc == 0 ? qT : kT) + (size_t)b * 128 * 1024;
        const float* bs = (wc == 0 ? bq : bk);
        const float bsc = (wc == 0) ? 1.44269504f : 1.0f;
#pragma unroll
        for (int nt = 0; nt < 2; ++nt) {
            const f32x16 a = nt ? acc1 : acc0;
            const int n = nblk * 128 + 64 * wn + 32 * nt + l31;
            uint* tb = (uint*)(dst + (size_t)(n >> 5) * 1024);
#pragma unroll
            for (int r = 0; r < 16; r += 2) {
                const int row = (r & 3) + 8 * (r >> 2) + 4 * h5;   // even
                tb[((row >> 4) & 1) * 256 + ((row >> 3) & 1) * 128 + (n & 31) * 4 + ((row & 7) >> 1)] =
                    pack2bf(a[r] + bs[row] * bsc, a[r + 1] + bs[row + 1] * bsc);
            }
        }
    }
}

// ---------------------------------------------------------------------------
// Flash attention v6: identical schedule to v5 (barrier-free main loop, wave
// (kg,cg) owns keys 1024*kg..+1024 x channels 128*cg..+128, P in-register via
// swapped QK^T + permlane32_swap, single end-of-kernel kg tree-reduction),
// but ALL Q/K/V fragment loads are lane-linear coalesced from tiled layouts.
// grid 256 (batch locked to XCD pair), block 512 (8 waves, 2/SIMD).
// ---------------------------------------------------------------------------
__global__ __attribute__((amdgpu_flat_work_group_size(512, 512), amdgpu_waves_per_eu(2, 2)))
void attn_v6(
    const ushort* __restrict__ qT, const ushort* __restrict__ kT,
    const ushort* __restrict__ v, float* __restrict__ out)
{
    const int bid  = blockIdx.x;
    const int xcd  = bid & 7;
    const int b    = xcd >> 1;                       // batch locked to XCD pair
    const int qblk = (bid >> 3) + 32 * (xcd & 1);
    const int i0   = qblk * 64;

    const int t    = threadIdx.x;
    const int w    = t >> 6;
    const int kg   = w >> 1;          // key group 0..3 (1024 keys each)
    const int cg   = w & 1;           // channel half 0..1 (128 ch each)
    const int lane = t & 63;
    const int l31  = lane & 31;
    const int h5   = lane >> 5;

    __shared__ f32x4 cbuf[2][2][4][2][4][64];   // 128 KB kg-reduction buffer
    __shared__ float red[2][4][32];             // 1 KB denominators [qt][kg][q]

    // fragment-tiled bases (all lane-linear: + frag*512u + lane*8u)
    const ushort* qTb = qT + (size_t)b * 128 * 1024 + lane * 8;
    const ushort* kTb = kT + ((size_t)b * 128 + kg * 32) * 1024 + lane * 8;
    const ushort* vfb = v + (((size_t)b * 8 + cg * 4) * 128 + kg * 32) * 1024 + lane * 8;

    // Q B-frags (col = query), both halves, contraction 32 in 2 ksteps
    bf16x8 qf[2][2];
#pragma unroll
    for (int qt = 0; qt < 2; ++qt)
#pragma unroll
        for (int ks = 0; ks < 2; ++ks)
            qf[qt][ks] = *reinterpret_cast<const bf16x8*>(
                qTb + (size_t)((i0 >> 5) + qt) * 1024 + ks * 512);

    const f32x16 z16 = {0,0,0,0, 0,0,0,0, 0,0,0,0, 0,0,0,0};
    f32x16 acc[4][2];
#pragma unroll
    for (int ct = 0; ct < 4; ++ct) { acc[ct][0] = z16; acc[ct][1] = z16; }
    float ts0 = 0.f, ts1 = 0.f;

    // K A-frags for it=0
    bf16x8 kf0 = *reinterpret_cast<const bf16x8*>(kTb);
    bf16x8 kf1 = *reinterpret_cast<const bf16x8*>(kTb + 512);

    auto expack = [&](const f32x16& s, float& ts, bf16x8& b0, bf16x8& b1) {
        float p[16];
#pragma unroll
        for (int r = 0; r < 16; ++r) p[r] = __builtin_exp2f(s[r]);
        ts += (((p[0]+p[1])+(p[2]+p[3])) + ((p[4]+p[5])+(p[6]+p[7])))
            + (((p[8]+p[9])+(p[10]+p[11])) + ((p[12]+p[13])+(p[14]+p[15])));
        const uint pk0 = pack2bf(p[0],  p[1]);
        const uint pk1 = pack2bf(p[2],  p[3]);
        const uint pk2 = pack2bf(p[4],  p[5]);
        const uint pk3 = pack2bf(p[6],  p[7]);
        const uint pk4 = pack2bf(p[8],  p[9]);
        const uint pk5 = pack2bf(p[10], p[11]);
        const uint pk6 = pack2bf(p[12], p[13]);
        const uint pk7 = pack2bf(p[14], p[15]);
        const u32x2 s02 = __builtin_amdgcn_permlane32_swap(pk0, pk2, false, false);
        const u32x2 s13 = __builtin_amdgcn_permlane32_swap(pk1, pk3, false, false);
        const u32x2 s46 = __builtin_amdgcn_permlane32_swap(pk4, pk6, false, false);
        const u32x2 s57 = __builtin_amdgcn_permlane32_swap(pk5, pk7, false, false);
        UB u0; u0.u = u32x4{ s02.x, s13.x, s02.y, s13.y };   // keys 8h5..+7   (ks0)
        UB u1; u1.u = u32x4{ s46.x, s57.x, s46.y, s57.y };   // keys 16+8h5..+7 (ks1)
        b0 = u0.h; b1 = u1.h;
    };

    for (int it = 0; it < 32; ++it) {
        // ---- issue V frags for this iter (coalesced 16-full-line loads) ----
        bf16x8 vf[4][2];
#pragma unroll
        for (int ct = 0; ct < 4; ++ct) {
            const ushort* vr = vfb + (size_t)ct * 128 * 1024 + (size_t)it * 1024;
            vf[ct][0] = *reinterpret_cast<const bf16x8*>(vr);
            vf[ct][1] = *reinterpret_cast<const bf16x8*>(vr + 512);
        }
        __builtin_amdgcn_sched_barrier(0);   // keep V issues above the S phase

        // ---- swapped S = K·Q^T on this wave's private 32-key chunk ----
        f32x16 s0 = __builtin_amdgcn_mfma_f32_32x32x16_bf16(kf0, qf[0][0], z16, 0, 0, 0);
        s0 = __builtin_amdgcn_mfma_f32_32x32x16_bf16(kf1, qf[0][1], s0, 0, 0, 0);
        f32x16 s1 = __builtin_amdgcn_mfma_f32_32x32x16_bf16(kf0, qf[1][0], z16, 0, 0, 0);
        s1 = __builtin_amdgcn_mfma_f32_32x32x16_bf16(kf1, qf[1][1], s1, 0, 0, 0);

        // ---- prefetch K frags for next iter (contiguous 2KB tile) ----
        if (it != 31) {
            const ushort* kr = kTb + (size_t)(it + 1) * 1024;
            kf0 = *reinterpret_cast<const bf16x8*>(kr);
            kf1 = *reinterpret_cast<const bf16x8*>(kr + 512);
        }

        // ---- exp + pack + permlane redistribute, fully in-register ----
        bf16x8 p00, p01, p10, p11;
        expack(s0, ts0, p00, p01);
        expack(s1, ts1, p10, p11);

        // ---- PV on own keys / own channels ----
#pragma unroll
        for (int ct = 0; ct < 4; ++ct) {
            acc[ct][0] = __builtin_amdgcn_mfma_f32_32x32x16_bf16(vf[ct][0], p00, acc[ct][0], 0, 0, 0);
            acc[ct][0] = __builtin_amdgcn_mfma_f32_32x32x16_bf16(vf[ct][1], p01, acc[ct][0], 0, 0, 0);
            acc[ct][1] = __builtin_amdgcn_mfma_f32_32x32x16_bf16(vf[ct][0], p10, acc[ct][1], 0, 0, 0);
            acc[ct][1] = __builtin_amdgcn_mfma_f32_32x32x16_bf16(vf[ct][1], p11, acc[ct][1], 0, 0, 0);
        }
    }

    // ---- denominators: sum key-halves, publish per-kg partials (cg0 only) ----
    ts0 += __shfl_xor(ts0, 32);
    ts1 += __shfl_xor(ts1, 32);
    if (cg == 0 && lane < 32) { red[0][kg][l31] = ts0; red[1][kg][l31] = ts1; }

    // ---- kg tree-reduction of acc through LDS (3 barriers) ----
    auto writeC = [&](int pair) {
#pragma unroll
        for (int ct = 0; ct < 4; ++ct)
#pragma unroll
            for (int qt = 0; qt < 2; ++qt)
#pragma unroll
                for (int rg = 0; rg < 4; ++rg) {
                    f32x4 vv = { acc[ct][qt][4*rg],   acc[ct][qt][4*rg+1],
                                 acc[ct][qt][4*rg+2], acc[ct][qt][4*rg+3] };
                    cbuf[pair][cg][ct][qt][rg][lane] = vv;
                }
    };
    auto addC = [&](int pair) {
#pragma unroll
        for (int ct = 0; ct < 4; ++ct)
#pragma unroll
            for (int qt = 0; qt < 2; ++qt)
#pragma unroll
                for (int rg = 0; rg < 4; ++rg) {
                    const f32x4 vv = cbuf[pair][cg][ct][qt][rg][lane];
                    acc[ct][qt][4*rg]   += vv.x;
                    acc[ct][qt][4*rg+1] += vv.y;
                    acc[ct][qt][4*rg+2] += vv.z;
                    acc[ct][qt][4*rg+3] += vv.w;
                }
    };

    if (kg >= 2) writeC(kg - 2);
    __syncthreads();
    if (kg < 2) addC(kg);
    __syncthreads();
    if (kg == 1) writeC(1);
    __syncthreads();
    if (kg == 0) {
        addC(1);
        const float inv0 = 1.0f / (red[0][0][l31] + red[0][1][l31] + red[0][2][l31] + red[0][3][l31]);
        const float inv1 = 1.0f / (red[1][0][l31] + red[1][1][l31] + red[1][2][l31] + red[1][3][l31]);
        float* ob = out + (size_t)b * CH * NN + i0;
#pragma unroll
        for (int ct = 0; ct < 4; ++ct)
#pragma unroll
            for (int qt = 0; qt < 2; ++qt) {
                const float inv = qt ? inv1 : inv0;
#pragma unroll
                for (int r = 0; r < 16; ++r) {
                    const int chl = 128 * cg + 32 * ct + (r & 3) + 8 * (r >> 2) + 4 * h5;
                    ob[(size_t)chl * NN + 32 * qt + l31] = acc[ct][qt][r] * inv;
                }
            }
    }
}

extern "C" void kernel_launch(void* const* d_in, const int* in_sizes, int n_in,
                              void* d_out, int out_size, void* d_ws, size_t ws_size,
                              hipStream_t stream) {
    const float* x  = (const float*)d_in[0];
    const float* Wq = (const float*)d_in[1];
    const float* bq = (const float*)d_in[2];
    const float* Wk = (const float*)d_in[3];
    const float* bk = (const float*)d_in[4];
    const float* Wv = (const float*)d_in[5];
    const float* bv = (const float*)d_in[6];
    float* out = (float*)d_out;

    ushort* ws = (ushort*)d_ws;
    ushort* qTf = ws;                                   // 4*128 tiles * 2KB = 1 MB
    ushort* kTf = qTf + (size_t)4 * 128 * 1024;         // 1 MB
    ushort* vf  = kTf + (size_t)4 * 128 * 1024;         // 4*8*128 tiles * 2KB = 8 MB

    proj_mfma<<<dim3(32, 5, 4), 256, 0, stream>>>(x, Wq, bq, Wk, bk, Wv, bv, qTf, kTf, vf);
    attn_v6<<<dim3(256), 512, 0, stream>>>(qTf, kTf, vf, out);
}

// Round 8
// 77.502 us; speedup vs baseline: 1.2974x; 1.0837x over previous
//
#include <hip/hip_runtime.h>
#include <hip/hip_bf16.h>

typedef __attribute__((ext_vector_type(8)))  short bf16x8;
typedef __attribute__((ext_vector_type(16))) float f32x16;
typedef __attribute__((ext_vector_type(4)))  float f32x4;
typedef __attribute__((ext_vector_type(2)))  unsigned int u32x2;
typedef __attribute__((ext_vector_type(4)))  unsigned int u32x4;

#define NN 4096
#define CH 256
#define CQ 32

union UB { u32x4 u; bf16x8 h; };

static __device__ __forceinline__ ushort f2bf(float f) {
    __hip_bfloat16 h = __float2bfloat16(f);
    return *reinterpret_cast<ushort*>(&h);
}
static __device__ __forceinline__ uint pack2bf(float a, float b) {
    return (uint)f2bf(a) | ((uint)f2bf(b) << 16);
}
// single-instruction bf16 pair pack (T12; RNE per HW cvt) — replaces ~12 VALU ops
static __device__ __forceinline__ uint cvt_pk_bf16(float a, float b) {
    uint r;
    asm("v_cvt_pk_bf16_f32 %0, %1, %2" : "=v"(r) : "v"(a), "v"(b));
    return r;
}
static __device__ __forceinline__ int swz(int n) {   // 3-bit 16B-slot swizzle
    return ((n & 7) ^ ((n >> 3) & 7)) << 4;
}

// ---------------------------------------------------------------------------
// Fragment-tiled workspace layouts (bf16, 32x32 tiles of 1024 ushorts,
// in-tile offset = frag*512u + lane*8u): see R7 notes. Frag loads are 64
// lanes x 16B = 16 full 64B lines.
// ---------------------------------------------------------------------------

// Fused Q/K/V projection, bf16 MFMA. grid (32 nblk, 5 chb, 4 b), block 256.
__global__ __launch_bounds__(256) void proj_mfma(
    const float* __restrict__ x,
    const float* __restrict__ Wq, const float* __restrict__ bq,
    const float* __restrict__ Wk, const float* __restrict__ bk,
    const float* __restrict__ Wv, const float* __restrict__ bv,
    ushort* __restrict__ qT, ushort* __restrict__ kT, ushort* __restrict__ v)
{
    const int nblk = blockIdx.x;
    const int chb  = blockIdx.y;
    const int b    = blockIdx.z;
    const int t    = threadIdx.x;
    const int w    = t >> 6;
    const int wc   = w >> 1, wn = w & 1;
    const int lane = t & 63;
    const int l31  = lane & 31;
    const int h5   = lane >> 5;

    __shared__ ushort Wl[64 * 256];     // 32 KB  [ch][c] bf16, 512B rows, swizzled
    __shared__ ushort Xl[128 * 64];     // 16 KB  [n][c]  bf16, 128B rows, swizzled

    // ---- stage W (64 out-ch x 256 c) fp32 -> bf16, once ----
    {
        const int ch  = t >> 2;
        const int c0  = (t & 3) * 64;
        const int chg = chb * 64 + ch;
        const float* wr; float sc = 1.0f;
        if (chg < 256)      wr = Wv + (size_t)chg * CH;
        else if (chg < 288) { wr = Wq + (size_t)(chg - 256) * CH; sc = 1.44269504f; }
        else                wr = Wk + (size_t)(chg - 288) * CH;
        const int sw = swz(ch);
#pragma unroll
        for (int j = 0; j < 16; ++j) {
            const int c = c0 + 4 * j;
            float4 f = *reinterpret_cast<const float4*>(wr + c);
            u32x2 p; p.x = pack2bf(f.x * sc, f.y * sc); p.y = pack2bf(f.z * sc, f.w * sc);
            *reinterpret_cast<u32x2*>((char*)Wl + ((ch * 512 + c * 2) ^ sw)) = p;
        }
    }

    const f32x16 z16 = {0,0,0,0, 0,0,0,0, 0,0,0,0, 0,0,0,0};
    f32x16 acc0 = z16, acc1 = z16;
    const float* xb = x + (size_t)b * CH * NN + nblk * 128;

    for (int cs = 0; cs < 4; ++cs) {
        if (cs) __syncthreads();
#pragma unroll
        for (int half = 0; half < 2; ++half) {
            const int cl0 = half * 32 + 4 * (t >> 5);
            const int nl0 = 4 * (t & 31);
            const float4 r0 = *reinterpret_cast<const float4*>(xb + (size_t)(cs*64 + cl0 + 0) * NN + nl0);
            const float4 r1 = *reinterpret_cast<const float4*>(xb + (size_t)(cs*64 + cl0 + 1) * NN + nl0);
            const float4 r2 = *reinterpret_cast<const float4*>(xb + (size_t)(cs*64 + cl0 + 2) * NN + nl0);
            const float4 r3 = *reinterpret_cast<const float4*>(xb + (size_t)(cs*64 + cl0 + 3) * NN + nl0);
#pragma unroll
            for (int e = 0; e < 4; ++e) {
                const int nl = nl0 + e;
                u32x2 p;
                p.x = pack2bf(((const float*)&r0)[e], ((const float*)&r1)[e]);
                p.y = pack2bf(((const float*)&r2)[e], ((const float*)&r3)[e]);
                *reinterpret_cast<u32x2*>((char*)Xl + ((nl * 128 + cl0 * 2) ^ swz(nl))) = p;
            }
        }
        __syncthreads();
#pragma unroll
        for (int kl = 0; kl < 4; ++kl) {
            const int ks  = cs * 4 + kl;
            const int chl = 32 * wc + l31;
            const bf16x8 af = *reinterpret_cast<const bf16x8*>(
                (char*)Wl + ((chl * 512 + ks * 32 + h5 * 16) ^ swz(chl)));
            {
                const int nl = 64 * wn + l31;
                const bf16x8 bfv = *reinterpret_cast<const bf16x8*>(
                    (char*)Xl + ((nl * 128 + kl * 32 + h5 * 16) ^ swz(nl)));
                acc0 = __builtin_amdgcn_mfma_f32_32x32x16_bf16(af, bfv, acc0, 0, 0, 0);
            }
            {
                const int nl = 64 * wn + 32 + l31;
                const bf16x8 bfv = *reinterpret_cast<const bf16x8*>(
                    (char*)Xl + ((nl * 128 + kl * 32 + h5 * 16) ^ swz(nl)));
                acc1 = __builtin_amdgcn_mfma_f32_32x32x16_bf16(af, bfv, acc1, 0, 0, 0);
            }
        }
    }

    // ---- epilogue: bias + store in fragment-tiled layouts ----
    const int chbase = chb * 64 + 32 * wc;
    if (chb < 4) {
        ushort* vtb = v + (size_t)b * 8 * 128 * 1024;
#pragma unroll
        for (int nt = 0; nt < 2; ++nt) {
            const f32x16 a = nt ? acc1 : acc0;
            const int key = nblk * 128 + 64 * wn + 32 * nt + l31;
            const size_t kb2 = (size_t)(key >> 5) * 1024
                             + ((key >> 4) & 1) * 512 + ((key >> 3) & 1) * 256 + (key & 7);
#pragma unroll
            for (int r = 0; r < 16; ++r) {
                const int ch = chbase + (r & 3) + 8 * (r >> 2) + 4 * h5;
                vtb[(size_t)(ch >> 5) * 128 * 1024 + kb2 + (ch & 31) * 8] = f2bf(a[r] + bv[ch]);
            }
        }
    } else {
        ushort* dst = (wc == 0 ? qT : kT) + (size_t)b * 128 * 1024;
        const float* bs = (wc == 0 ? bq : bk);
        const float bsc = (wc == 0) ? 1.44269504f : 1.0f;
#pragma unroll
        for (int nt = 0; nt < 2; ++nt) {
            const f32x16 a = nt ? acc1 : acc0;
            const int n = nblk * 128 + 64 * wn + 32 * nt + l31;
            uint* tb = (uint*)(dst + (size_t)(n >> 5) * 1024);
#pragma unroll
            for (int r = 0; r < 16; r += 2) {
                const int row = (r & 3) + 8 * (r >> 2) + 4 * h5;   // even
                tb[((row >> 4) & 1) * 256 + ((row >> 3) & 1) * 128 + (n & 31) * 4 + ((row & 7) >> 1)] =
                    pack2bf(a[r] + bs[row] * bsc, a[r + 1] + bs[row + 1] * bsc);
            }
        }
    }
}

// ---------------------------------------------------------------------------
// Flash attention v7: v6 schedule (barrier-free main loop, wave (kg,cg) owns
// keys 1024*kg..+1024 x channels 128*cg..+128, P in-register via swapped QK^T
// + cvt_pk + permlane32_swap, single end-of-kernel kg tree-reduction) with
// VALU cuts: asm v_cvt_pk_bf16_f32 packing, wave-uniform SGPR walking bases
// for V/K (lane offset folded at deref -> SALU addressing).
// grid 256 (batch locked to XCD pair), block 512 (8 waves, 2/SIMD).
// ---------------------------------------------------------------------------
__global__ __attribute__((amdgpu_flat_work_group_size(512, 512), amdgpu_waves_per_eu(2, 2)))
void attn_v7(
    const ushort* __restrict__ qT, const ushort* __restrict__ kT,
    const ushort* __restrict__ v, float* __restrict__ out)
{
    const int bid  = blockIdx.x;
    const int xcd  = bid & 7;
    const int b    = xcd >> 1;                       // batch locked to XCD pair
    const int qblk = (bid >> 3) + 32 * (xcd & 1);
    const int i0   = qblk * 64;

    const int t    = threadIdx.x;
    const int w    = t >> 6;
    const int kg   = w >> 1;          // key group 0..3 (1024 keys each)
    const int cg   = w & 1;           // channel half 0..1 (128 ch each)
    const int lane = t & 63;
    const int l31  = lane & 31;
    const int h5   = lane >> 5;
    const int lo8  = lane * 8;        // frag lane offset (ushort units)

    __shared__ f32x4 cbuf[2][2][4][2][4][64];   // 128 KB kg-reduction buffer
    __shared__ float red[2][4][32];             // 1 KB denominators [qt][kg][q]

    // wave-uniform bases (lane offset added only at deref -> SGPR base + voffset)
    const ushort* qTu = qT + (size_t)b * 128 * 1024;
    const ushort* kTu = kT + ((size_t)b * 128 + kg * 32) * 1024;
    const ushort* vfu = v + (((size_t)b * 8 + cg * 4) * 128 + kg * 32) * 1024;

    // Q B-frags (col = query), both halves, contraction 32 in 2 ksteps
    bf16x8 qf[2][2];
#pragma unroll
    for (int qt = 0; qt < 2; ++qt)
#pragma unroll
        for (int ks = 0; ks < 2; ++ks)
            qf[qt][ks] = *reinterpret_cast<const bf16x8*>(
                qTu + (size_t)((i0 >> 5) + qt) * 1024 + ks * 512 + lo8);

    const f32x16 z16 = {0,0,0,0, 0,0,0,0, 0,0,0,0, 0,0,0,0};
    f32x16 acc[4][2];
#pragma unroll
    for (int ct = 0; ct < 4; ++ct) { acc[ct][0] = z16; acc[ct][1] = z16; }
    float ts0 = 0.f, ts1 = 0.f;

    // K A-frags for it=0
    bf16x8 kf0 = *reinterpret_cast<const bf16x8*>(kTu + lo8);
    bf16x8 kf1 = *reinterpret_cast<const bf16x8*>(kTu + 512 + lo8);

    auto expack = [&](const f32x16& s, float& ts, bf16x8& b0, bf16x8& b1) {
        float p[16];
#pragma unroll
        for (int r = 0; r < 16; ++r) p[r] = __builtin_exp2f(s[r]);
        ts += (((p[0]+p[1])+(p[2]+p[3])) + ((p[4]+p[5])+(p[6]+p[7])))
            + (((p[8]+p[9])+(p[10]+p[11])) + ((p[12]+p[13])+(p[14]+p[15])));
        const uint pk0 = cvt_pk_bf16(p[0],  p[1]);
        const uint pk1 = cvt_pk_bf16(p[2],  p[3]);
        const uint pk2 = cvt_pk_bf16(p[4],  p[5]);
        const uint pk3 = cvt_pk_bf16(p[6],  p[7]);
        const uint pk4 = cvt_pk_bf16(p[8],  p[9]);
        const uint pk5 = cvt_pk_bf16(p[10], p[11]);
        const uint pk6 = cvt_pk_bf16(p[12], p[13]);
        const uint pk7 = cvt_pk_bf16(p[14], p[15]);
        const u32x2 s02 = __builtin_amdgcn_permlane32_swap(pk0, pk2, false, false);
        const u32x2 s13 = __builtin_amdgcn_permlane32_swap(pk1, pk3, false, false);
        const u32x2 s46 = __builtin_amdgcn_permlane32_swap(pk4, pk6, false, false);
        const u32x2 s57 = __builtin_amdgcn_permlane32_swap(pk5, pk7, false, false);
        UB u0; u0.u = u32x4{ s02.x, s13.x, s02.y, s13.y };   // keys 8h5..+7   (ks0)
        UB u1; u1.u = u32x4{ s46.x, s57.x, s46.y, s57.y };   // keys 16+8h5..+7 (ks1)
        b0 = u0.h; b1 = u1.h;
    };

    for (int it = 0; it < 32; ++it) {
        // ---- issue V frags for this iter (uniform base walk, coalesced) ----
        bf16x8 vf[4][2];
#pragma unroll
        for (int ct = 0; ct < 4; ++ct) {
            const ushort* vr = vfu + (size_t)ct * 131072 + (size_t)it * 1024;
            vf[ct][0] = *reinterpret_cast<const bf16x8*>(vr + lo8);
            vf[ct][1] = *reinterpret_cast<const bf16x8*>(vr + 512 + lo8);
        }
        __builtin_amdgcn_sched_barrier(0);   // keep V issues above the S phase

        // ---- swapped S = K·Q^T on this wave's private 32-key chunk ----
        f32x16 s0 = __builtin_amdgcn_mfma_f32_32x32x16_bf16(kf0, qf[0][0], z16, 0, 0, 0);
        s0 = __builtin_amdgcn_mfma_f32_32x32x16_bf16(kf1, qf[0][1], s0, 0, 0, 0);
        f32x16 s1 = __builtin_amdgcn_mfma_f32_32x32x16_bf16(kf0, qf[1][0], z16, 0, 0, 0);
        s1 = __builtin_amdgcn_mfma_f32_32x32x16_bf16(kf1, qf[1][1], s1, 0, 0, 0);

        // ---- prefetch K frags for next iter (uniform base walk) ----
        if (it != 31) {
            const ushort* kr = kTu + (size_t)(it + 1) * 1024;
            kf0 = *reinterpret_cast<const bf16x8*>(kr + lo8);
            kf1 = *reinterpret_cast<const bf16x8*>(kr + 512 + lo8);
        }

        // ---- exp + cvt_pk + permlane redistribute, fully in-register ----
        bf16x8 p00, p01, p10, p11;
        expack(s0, ts0, p00, p01);
        expack(s1, ts1, p10, p11);

        // ---- PV on own keys / own channels ----
#pragma unroll
        for (int ct = 0; ct < 4; ++ct) {
            acc[ct][0] = __builtin_amdgcn_mfma_f32_32x32x16_bf16(vf[ct][0], p00, acc[ct][0], 0, 0, 0);
            acc[ct][0] = __builtin_amdgcn_mfma_f32_32x32x16_bf16(vf[ct][1], p01, acc[ct][0], 0, 0, 0);
            acc[ct][1] = __builtin_amdgcn_mfma_f32_32x32x16_bf16(vf[ct][0], p10, acc[ct][1], 0, 0, 0);
            acc[ct][1] = __builtin_amdgcn_mfma_f32_32x32x16_bf16(vf[ct][1], p11, acc[ct][1], 0, 0, 0);
        }
    }

    // ---- denominators: sum key-halves, publish per-kg partials (cg0 only) ----
    ts0 += __shfl_xor(ts0, 32);
    ts1 += __shfl_xor(ts1, 32);
    if (cg == 0 && lane < 32) { red[0][kg][l31] = ts0; red[1][kg][l31] = ts1; }

    // ---- kg tree-reduction of acc through LDS (3 barriers) ----
    auto writeC = [&](int pair) {
#pragma unroll
        for (int ct = 0; ct < 4; ++ct)
#pragma unroll
            for (int qt = 0; qt < 2; ++qt)
#pragma unroll
                for (int rg = 0; rg < 4; ++rg) {
                    f32x4 vv = { acc[ct][qt][4*rg],   acc[ct][qt][4*rg+1],
                                 acc[ct][qt][4*rg+2], acc[ct][qt][4*rg+3] };
                    cbuf[pair][cg][ct][qt][rg][lane] = vv;
                }
    };
    auto addC = [&](int pair) {
#pragma unroll
        for (int ct = 0; ct < 4; ++ct)
#pragma unroll
            for (int qt = 0; qt < 2; ++qt)
#pragma unroll
                for (int rg = 0; rg < 4; ++rg) {
                    const f32x4 vv = cbuf[pair][cg][ct][qt][rg][lane];
                    acc[ct][qt][4*rg]   += vv.x;
                    acc[ct][qt][4*rg+1] += vv.y;
                    acc[ct][qt][4*rg+2] += vv.z;
                    acc[ct][qt][4*rg+3] += vv.w;
                }
    };

    if (kg >= 2) writeC(kg - 2);
    __syncthreads();
    if (kg < 2) addC(kg);
    __syncthreads();
    if (kg == 1) writeC(1);
    __syncthreads();
    if (kg == 0) {
        addC(1);
        const float inv0 = 1.0f / (red[0][0][l31] + red[0][1][l31] + red[0][2][l31] + red[0][3][l31]);
        const float inv1 = 1.0f / (red[1][0][l31] + red[1][1][l31] + red[1][2][l31] + red[1][3][l31]);
        float* ob = out + (size_t)b * CH * NN + i0;
#pragma unroll
        for (int ct = 0; ct < 4; ++ct)
#pragma unroll
            for (int qt = 0; qt < 2; ++qt) {
                const float inv = qt ? inv1 : inv0;
#pragma unroll
                for (int r = 0; r < 16; ++r) {
                    const int chl = 128 * cg + 32 * ct + (r & 3) + 8 * (r >> 2) + 4 * h5;
                    ob[(size_t)chl * NN + 32 * qt + l31] = acc[ct][qt][r] * inv;
                }
            }
    }
}

extern "C" void kernel_launch(void* const* d_in, const int* in_sizes, int n_in,
                              void* d_out, int out_size, void* d_ws, size_t ws_size,
                              hipStream_t stream) {
    const float* x  = (const float*)d_in[0];
    const float* Wq = (const float*)d_in[1];
    const float* bq = (const float*)d_in[2];
    const float* Wk = (const float*)d_in[3];
    const float* bk = (const float*)d_in[4];
    const float* Wv = (const float*)d_in[5];
    const float* bv = (const float*)d_in[6];
    float* out = (float*)d_out;

    ushort* ws = (ushort*)d_ws;
    ushort* qTf = ws;                                   // 4*128 tiles * 2KB = 1 MB
    ushort* kTf = qTf + (size_t)4 * 128 * 1024;         // 1 MB
    ushort* vf  = kTf + (size_t)4 * 128 * 1024;         // 4*8*128 tiles * 2KB = 8 MB

    proj_mfma<<<dim3(32, 5, 4), 256, 0, stream>>>(x, Wq, bq, Wk, bk, Wv, bv, qTf, kTf, vf);
    attn_v7<<<dim3(256), 512, 0, stream>>>(qTf, kTf, vf, out);
}